// Round 9
// baseline (391.314 us; speedup 1.0000x reference)
//
#include <hip/hip_runtime.h>
#include <hip/hip_fp16.h>
#include <math.h>

#define NNODES 30000
#define MPAD   30080          // padded Z row count per relation (470*64)
#define NEDGES 300000
#define NREL 3
#define IND 256
#define HIDD 32
#define OUTD 64
#define NHEADS 4
#define C1 (NHEADS*HIDD)    // 128
#define C2 (NHEADS*OUTD)    // 256
#define NEG_SLOPE 0.2f
#define CAP 64              // max in-degree per (rel,node); Poisson(10) -> P(>=64) ~ 1e-30

typedef _Float16 f16x8 __attribute__((ext_vector_type(8)));
typedef float f32x4  __attribute__((ext_vector_type(4)));

// ---- f16 <-> f32 helpers ----
__device__ __forceinline__ unsigned short f2h(float f) {
    union { __half h; unsigned short u; } c; c.h = __float2half_rn(f); return c.u;
}
__device__ __forceinline__ float h2f(unsigned short u) {
    union { unsigned short u; __half h; } c; c.u = u; return __half2float(c.h);
}
__device__ __forceinline__ __half2 u2h2(unsigned u) {
    union { unsigned u; __half2 h; } c; c.u = u; return c.h;
}

// ---- pack W[r] (row-major KxN fp32) into MFMA B-fragment order, f16 ----
template<int K, int N>
__device__ __forceinline__ void pack_w_dev(const float* __restrict__ W,
                                           unsigned short* __restrict__ P, int t) {
    const int KS = K / 32, NT = N / 16;
    int lane = t & 63;
    int fid = t >> 6;
    if (fid >= NREL * NT * KS) return;
    int ks = fid % KS;
    int nt = (fid / KS) % NT;
    int r  = fid / (KS * NT);
    int n  = nt * 16 + (lane & 15);
    int k0 = ks * 32 + (lane >> 4) * 8;
    const float* Wr = W + (size_t)r * K * N;
    unsigned short o[8];
#pragma unroll
    for (int j = 0; j < 8; j++) o[j] = f2h(Wr[(size_t)(k0 + j) * N + n]);
    unsigned short* dst = P + (size_t)fid * 512 + lane * 8;
    *(ushort4*)&dst[0] = *(ushort4*)&o[0];
    *(ushort4*)&dst[4] = *(ushort4*)&o[4];
}

// ---- fused prep: x->f16 cast | pack W1 | pack W2 | bucket_fill ----
#define CAST_BLOCKS (NNODES * IND / 4 / 256)          // 7500
#define PACK1_BLOCKS (NREL * (C1/16) * (IND/32) / 4)  // 48
#define PACK2_BLOCKS (NREL * (C2/16) * (C1/32) / 4)   // 48
#define BUCK_BLOCKS  ((NREL * NEDGES + 255) / 256)    // 3516
__global__ void prep_kernel(const float* __restrict__ x, unsigned short* __restrict__ Xh,
                            const float* __restrict__ W1, unsigned short* __restrict__ P1,
                            const float* __restrict__ W2, unsigned short* __restrict__ P2,
                            const int* __restrict__ src, const int* __restrict__ dst,
                            unsigned* __restrict__ cnt, int* __restrict__ buck) {
    int b = blockIdx.x;
    if (b < CAST_BLOCKS) {
        int i = (b * 256 + threadIdx.x) * 4;
        float4 v = *(const float4*)&x[i];
        ushort4 o = { f2h(v.x), f2h(v.y), f2h(v.z), f2h(v.w) };
        *(ushort4*)&Xh[i] = o;
    } else if (b < CAST_BLOCKS + PACK1_BLOCKS) {
        pack_w_dev<IND, C1>(W1, P1, (b - CAST_BLOCKS) * 256 + threadIdx.x);
    } else if (b < CAST_BLOCKS + PACK1_BLOCKS + PACK2_BLOCKS) {
        pack_w_dev<C1, C2>(W2, P2, (b - CAST_BLOCKS - PACK1_BLOCKS) * 256 + threadIdx.x);
    } else {
        int gid = (b - CAST_BLOCKS - PACK1_BLOCKS - PACK2_BLOCKS) * 256 + threadIdx.x;
        if (gid < NREL * NEDGES) {
            int r = gid / NEDGES;
            int d = dst[gid];
            int base = r * NNODES + d;
            unsigned pos = atomicAdd(&cnt[base], 1u);
            if (pos < CAP) buck[(size_t)base * CAP + pos] = src[gid];
        }
    }
}

// ---- MFMA GEMM + fused coeff, one (relation, 64-row tile) per block ----
template<int K, int N>
__global__ __launch_bounds__(256) void mfma_gemm(
    const unsigned short* __restrict__ Ah, const unsigned short* __restrict__ Bp,
    const float* __restrict__ al, const float* __restrict__ ar,
    unsigned short* __restrict__ Zh, float* __restrict__ el, float* __restrict__ er)
{
    const int KS = K / 32, NT = N / 16, MT = 64, NP = N + 4;
    const int wave = threadIdx.x >> 6, lane = threadIdx.x & 63;
    const int r  = blockIdx.y;
    const int m0 = blockIdx.x * MT;
    const int fcol = lane & 15, quad = lane >> 4;

    __shared__ unsigned short zs[MT * (N + 4)];

    int m = m0 + wave * 16 + fcol;
    if (m >= NNODES) m = NNODES - 1;           // clamp; padded rows never consumed
    f16x8 afrag[KS];
    const unsigned short* arow = Ah + (size_t)m * K + quad * 8;
#pragma unroll
    for (int ks = 0; ks < KS; ks++) afrag[ks] = *(const f16x8*)(arow + ks * 32);

    f32x4 acc[NT];
#pragma unroll
    for (int nt = 0; nt < NT; nt++) { f32x4 z = {0.f,0.f,0.f,0.f}; acc[nt] = z; }

    const unsigned short* Bpr = Bp + (size_t)r * NT * KS * 512;
    for (int ks = 0; ks < KS; ks++) {
        f16x8 b[NT];
#pragma unroll
        for (int nt = 0; nt < NT; nt++)
            b[nt] = *(const f16x8*)(Bpr + ((size_t)nt * KS + ks) * 512 + lane * 8);
#pragma unroll
        for (int nt = 0; nt < NT; nt++)
            acc[nt] = __builtin_amdgcn_mfma_f32_16x16x32_f16(afrag[ks], b[nt], acc[nt], 0, 0, 0);
    }

    {
        int lrow = wave * 16 + quad * 4;
#pragma unroll
        for (int nt = 0; nt < NT; nt++)
#pragma unroll
            for (int q = 0; q < 4; q++)
                zs[(lrow + q) * NP + nt * 16 + fcol] = f2h(acc[nt][q]);
    }
    __syncthreads();

    {
        uint2* zo = (uint2*)(Zh + ((size_t)r * MPAD + m0) * N);
        for (int i = threadIdx.x; i < MT * N / 4; i += 256) {
            int row = i / (N / 4), c4 = i % (N / 4);
            zo[i] = *(const uint2*)&zs[row * NP + c4 * 4];
        }
    }
    {
        const int D = N / NHEADS;
        int row = threadIdx.x >> 2, h = threadIdx.x & 3;   // MT*NHEADS == 256
        int n = m0 + row;
        if (n < NNODES) {
            const float* alp = al + ((size_t)r * NHEADS + h) * D;
            const float* arp = ar + ((size_t)r * NHEADS + h) * D;
            const unsigned short* zp = zs + row * NP + h * D;
            float sl = 0.f, sr = 0.f;
#pragma unroll
            for (int d0 = 0; d0 < D; d0 += 4) {
                uint2 u = *(const uint2*)&zp[d0];
                __half2 p0 = u2h2(u.x), p1 = u2h2(u.y);
                float z0 = __low2float(p0), z1 = __high2float(p0);
                float z2 = __low2float(p1), z3 = __high2float(p1);
                sl = fmaf(z0, alp[d0], sl);     sr = fmaf(z0, arp[d0], sr);
                sl = fmaf(z1, alp[d0 + 1], sl); sr = fmaf(z1, arp[d0 + 1], sr);
                sl = fmaf(z2, alp[d0 + 2], sl); sr = fmaf(z2, arp[d0 + 2], sr);
                sl = fmaf(z3, alp[d0 + 3], sl); sr = fmaf(z3, arp[d0 + 3], sr);
            }
            el[((size_t)r * NNODES + n) * NHEADS + h] = sl;
            er[((size_t)r * NNODES + n) * NHEADS + h] = sr;
        }
    }
}

// butterfly max/sum over 16 lanes, extended to 64 only when needed (wave-uniform)
__device__ __forceinline__ float red_max(float t, bool full) {
#pragma unroll
    for (int o = 1; o < 16; o <<= 1) t = fmaxf(t, __shfl_xor(t, o, 64));
    if (full) { t = fmaxf(t, __shfl_xor(t, 16, 64)); t = fmaxf(t, __shfl_xor(t, 32, 64)); }
    return t;
}
__device__ __forceinline__ float red_sum(float t, bool full) {
#pragma unroll
    for (int o = 1; o < 16; o <<= 1) t += __shfl_xor(t, o, 64);
    if (full) { t += __shfl_xor(t, 16, 64); t += __shfl_xor(t, 32, 64); }
    return t;
}

// ---- layer-1 aggregate: 2 waves per node (head-pair split), lane owns 1 ch ----
// wave w in {0,1} handles heads {2w, 2w+1} = channels [w*64, w*64+64) of C1=128
__global__ __launch_bounds__(256) void gat_gather1(
    const unsigned* __restrict__ cnt, const int* __restrict__ buck,
    const float* __restrict__ el, const float* __restrict__ er,
    const unsigned short* __restrict__ Zh, const float* __restrict__ b1,
    unsigned short* __restrict__ hbh)
{
    __shared__ float atab[4][NREL][2 * 65 + 2];  // per-wave, PER-RELATION alpha table
    const int wave = threadIdx.x >> 6, lane = threadIdx.x & 63;
    const int w = wave & 1;
    const int n = blockIdx.x * 2 + (wave >> 1);
    const int h0l = lane >> 5;           // which head of my pair owns this lane
    const int cch = w * 64 + lane;       // my channel; head = cch>>5 = 2w + h0l

    // ---- prefetch all relations (independent load chains) ----
    int cA[NREL], slR[NREL];
    float2 e2[NREL], r2[NREL];
#pragma unroll
    for (int r = 0; r < NREL; r++) {
        int base = r * NNODES + n;
        cA[r]  = (int)cnt[base];
        slR[r] = buck[(size_t)base * CAP + lane];
        r2[r]  = *(const float2*)&er[(size_t)base * NHEADS + 2 * w];
    }
#pragma unroll
    for (int r = 0; r < NREL; r++) {
        int c = cA[r] < CAP ? cA[r] : CAP; cA[r] = c;
        int sS = (lane < c) ? slR[r] : 0;
        e2[r] = *(const float2*)&el[((size_t)r * NNODES + sS) * NHEADS + 2 * w];
    }
    // ---- softmax (2 heads per wave) into atab[wave][r] ----
#pragma unroll
    for (int r = 0; r < NREL; r++) {
        int c = cA[r]; if (c == 0) continue;
        bool act = lane < c, full = c > 16;
        float v, lg[2];
        v = e2[r].x + r2[r].x; lg[0] = act ? (v > 0.f ? v : NEG_SLOPE * v) : -INFINITY;
        v = e2[r].y + r2[r].y; lg[1] = act ? (v > 0.f ? v : NEG_SLOPE * v) : -INFINITY;
#pragma unroll
        for (int h = 0; h < 2; h++) {
            float m = red_max(lg[h], full);
            float ww = act ? __expf(lg[h] - m) : 0.f;
            float den = red_sum(ww, full);
            atab[wave][r][h * 65 + lane] = ww / den;   // wave-private; no barrier
        }
    }
    // ---- gather (2B/lane rows; 2 waves/node => 8 rows in flight) ----
    float acc = 0.f;
#pragma unroll
    for (int r = 0; r < NREL; r++) {
        int c = cA[r]; if (c == 0) continue;
        int s_lane = slR[r];
        const unsigned short* Zr = Zh + (size_t)r * MPAD * C1 + cch;
        const float* at = atab[wave][r] + h0l * 65;
        int j = 0;
        for (; j + 3 < c; j += 4) {
            int s0 = __builtin_amdgcn_readlane(s_lane, j);
            int s1 = __builtin_amdgcn_readlane(s_lane, j + 1);
            int s2 = __builtin_amdgcn_readlane(s_lane, j + 2);
            int s3 = __builtin_amdgcn_readlane(s_lane, j + 3);
            unsigned short za = Zr[(size_t)s0 * C1];
            unsigned short zb = Zr[(size_t)s1 * C1];
            unsigned short zc = Zr[(size_t)s2 * C1];
            unsigned short zd = Zr[(size_t)s3 * C1];
            acc = fmaf(at[j],     h2f(za), acc);
            acc = fmaf(at[j + 1], h2f(zb), acc);
            acc = fmaf(at[j + 2], h2f(zc), acc);
            acc = fmaf(at[j + 3], h2f(zd), acc);
        }
        for (; j < c; j++) {
            int s = __builtin_amdgcn_readlane(s_lane, j);
            acc = fmaf(at[j], h2f(Zr[(size_t)s * C1]), acc);
        }
    }
    float b = b1[cch] + b1[C1 + cch] + b1[2 * C1 + cch];
    hbh[(size_t)n * C1 + cch] = f2h(fmaxf(acc + b, 0.f));
}

// ---- layer-2 aggregate: 2 waves per node (head-pair split), lane owns 2 ch ----
// wave w handles heads {2w, 2w+1} = channels [w*128, w*128+128) of C2=256
__global__ __launch_bounds__(256) void gat_gather2(
    const unsigned* __restrict__ cnt, const int* __restrict__ buck,
    const float* __restrict__ el, const float* __restrict__ er,
    const unsigned short* __restrict__ Zh, const float* __restrict__ b2,
    float* __restrict__ out)
{
    __shared__ float atab[4][NREL][2 * 65 + 2];
    __shared__ float part[2][64];
    const int wave = threadIdx.x >> 6, lane = threadIdx.x & 63;
    const int w = wave & 1, nloc = wave >> 1;
    const int n = blockIdx.x * 2 + nloc;
    const int h0l = lane >> 5;
    const int cch = w * 128 + 2 * lane;  // my channels cch, cch+1; head = cch>>6

    int cA[NREL], slR[NREL];
    float2 e2[NREL], r2[NREL];
#pragma unroll
    for (int r = 0; r < NREL; r++) {
        int base = r * NNODES + n;
        cA[r]  = (int)cnt[base];
        slR[r] = buck[(size_t)base * CAP + lane];
        r2[r]  = *(const float2*)&er[(size_t)base * NHEADS + 2 * w];
    }
#pragma unroll
    for (int r = 0; r < NREL; r++) {
        int c = cA[r] < CAP ? cA[r] : CAP; cA[r] = c;
        int sS = (lane < c) ? slR[r] : 0;
        e2[r] = *(const float2*)&el[((size_t)r * NNODES + sS) * NHEADS + 2 * w];
    }
#pragma unroll
    for (int r = 0; r < NREL; r++) {
        int c = cA[r]; if (c == 0) continue;
        bool act = lane < c, full = c > 16;
        float v, lg[2];
        v = e2[r].x + r2[r].x; lg[0] = act ? (v > 0.f ? v : NEG_SLOPE * v) : -INFINITY;
        v = e2[r].y + r2[r].y; lg[1] = act ? (v > 0.f ? v : NEG_SLOPE * v) : -INFINITY;
#pragma unroll
        for (int h = 0; h < 2; h++) {
            float m = red_max(lg[h], full);
            float ww = act ? __expf(lg[h] - m) : 0.f;
            float den = red_sum(ww, full);
            atab[wave][r][h * 65 + lane] = ww / den;
        }
    }
    float accx = 0.f, accy = 0.f;
#pragma unroll
    for (int r = 0; r < NREL; r++) {
        int c = cA[r]; if (c == 0) continue;
        int s_lane = slR[r];
        const unsigned short* Zr = Zh + (size_t)r * MPAD * C2 + cch;
        const float* at = atab[wave][r] + h0l * 65;
        int j = 0;
        for (; j + 3 < c; j += 4) {
            int s0 = __builtin_amdgcn_readlane(s_lane, j);
            int s1 = __builtin_amdgcn_readlane(s_lane, j + 1);
            int s2 = __builtin_amdgcn_readlane(s_lane, j + 2);
            int s3 = __builtin_amdgcn_readlane(s_lane, j + 3);
            unsigned ua = *(const unsigned*)&Zr[(size_t)s0 * C2];
            unsigned ub = *(const unsigned*)&Zr[(size_t)s1 * C2];
            unsigned uc = *(const unsigned*)&Zr[(size_t)s2 * C2];
            unsigned ud = *(const unsigned*)&Zr[(size_t)s3 * C2];
            float a0 = at[j], a1 = at[j + 1], a2 = at[j + 2], a3 = at[j + 3];
            __half2 p;
            p = u2h2(ua); accx = fmaf(a0, __low2float(p), accx); accy = fmaf(a0, __high2float(p), accy);
            p = u2h2(ub); accx = fmaf(a1, __low2float(p), accx); accy = fmaf(a1, __high2float(p), accy);
            p = u2h2(uc); accx = fmaf(a2, __low2float(p), accx); accy = fmaf(a2, __high2float(p), accy);
            p = u2h2(ud); accx = fmaf(a3, __low2float(p), accx); accy = fmaf(a3, __high2float(p), accy);
        }
        for (; j < c; j++) {
            int s = __builtin_amdgcn_readlane(s_lane, j);
            __half2 p = u2h2(*(const unsigned*)&Zr[(size_t)s * C2]);
            accx = fmaf(at[j], __low2float(p), accx);
            accy = fmaf(at[j], __high2float(p), accy);
        }
    }
    // bias (per my channels), then sum my head pair (lane ^ 32 holds other head, same o)
    accx += b2[cch]     + b2[C2 + cch]     + b2[2 * C2 + cch];
    accy += b2[cch + 1] + b2[C2 + cch + 1] + b2[2 * C2 + cch + 1];
    accx += __shfl_xor(accx, 32, 64);
    accy += __shfl_xor(accy, 32, 64);
    // cross-wave combine (heads {0,1} + {2,3}) via LDS; exact grid -> no divergence
    if (w == 1 && lane < 32) { part[nloc][2 * lane] = accx; part[nloc][2 * lane + 1] = accy; }
    __syncthreads();
    if (w == 0 && lane < 32) {
        float2 o;
        o.x = 0.25f * (accx + part[nloc][2 * lane]);
        o.y = 0.25f * (accy + part[nloc][2 * lane + 1]);
        *(float2*)&out[(size_t)n * OUTD + 2 * lane] = o;
    }
}

extern "C" void kernel_launch(void* const* d_in, const int* in_sizes, int n_in,
                              void* d_out, int out_size, void* d_ws, size_t ws_size,
                              hipStream_t stream) {
    (void)in_sizes; (void)n_in; (void)out_size; (void)ws_size;
    const float* x   = (const float*)d_in[0];
    const int*   src = (const int*)d_in[1];
    const int*   dst = (const int*)d_in[2];
    const float* W1  = (const float*)d_in[3];
    const float* al1 = (const float*)d_in[4];
    const float* ar1 = (const float*)d_in[5];
    const float* b1  = (const float*)d_in[6];
    const float* W2  = (const float*)d_in[7];
    const float* al2 = (const float*)d_in[8];
    const float* ar2 = (const float*)d_in[9];
    const float* b2  = (const float*)d_in[10];
    float* out = (float*)d_out;

    // ---- workspace layout (float-offset based; every chunk 16B-aligned) ----
    float* ws = (float*)d_ws;
    size_t off = 0;
    unsigned short* Zh  = (unsigned short*)(ws + off); off += (size_t)NREL * MPAD * C2 / 2;
    unsigned short* Xh  = (unsigned short*)(ws + off); off += (size_t)NNODES * IND / 2;
    unsigned short* hbh = (unsigned short*)(ws + off); off += (size_t)NNODES * C1 / 2;
    unsigned short* P1  = (unsigned short*)(ws + off); off += (size_t)NREL * (C1/16) * (IND/32) * 512 / 2;
    unsigned short* P2  = (unsigned short*)(ws + off); off += (size_t)NREL * (C2/16) * (C1/32) * 512 / 2;
    float* el  = ws + off; off += (size_t)NREL * NNODES * NHEADS;
    float* er  = ws + off; off += (size_t)NREL * NNODES * NHEADS;
    unsigned* cnt = (unsigned*)(ws + off); off += (size_t)NREL * NNODES;
    int* buck  = (int*)(ws + off); off += (size_t)NREL * NNODES * CAP;

    const int TB = 256;

    // ---- fused prep: cast + packs + adjacency build ----
    hipMemsetAsync(cnt, 0, (size_t)NREL * NNODES * sizeof(unsigned), stream);
    prep_kernel<<<CAST_BLOCKS + PACK1_BLOCKS + PACK2_BLOCKS + BUCK_BLOCKS, TB, 0, stream>>>(
        x, Xh, W1, P1, W2, P2, src, dst, cnt, buck);

    // ================= layer 1 =================
    {
        dim3 grid(MPAD / 64, NREL);
        mfma_gemm<IND, C1><<<grid, 256, 0, stream>>>(Xh, P1, al1, ar1, Zh, el, er);
    }
    gat_gather1<<<NNODES / 2, 256, 0, stream>>>(cnt, buck, el, er, Zh, b1, hbh);

    // ================= layer 2 =================
    {
        dim3 grid(MPAD / 64, NREL);
        mfma_gemm<C1, C2><<<grid, 256, 0, stream>>>(hbh, P2, al2, ar2, Zh, el, er);
    }
    gat_gather2<<<NNODES / 2, 256, 0, stream>>>(cnt, buck, el, er, Zh, b2, out);
}

// Round 11
// 367.846 us; speedup vs baseline: 1.0638x; 1.0638x over previous
//
#include <hip/hip_runtime.h>
#include <math.h>

#define NNODES 30000
#define MPAD   30080          // padded Z row count per relation (470*64)
#define NEDGES 300000
#define NREL 3
#define IND 256
#define HIDD 32
#define OUTD 64
#define NHEADS 4
#define C1 (NHEADS*HIDD)    // 128
#define C2 (NHEADS*OUTD)    // 256
#define NEG_SLOPE 0.2f
#define CAP 64              // max in-degree per (rel,node); Poisson(10) -> P(>=64) ~ 1e-30

typedef short bf16x8 __attribute__((ext_vector_type(8)));
typedef float f32x4  __attribute__((ext_vector_type(4)));

// ---- bf16 <-> f32 helpers (RNE pack; exact unpack) ----
__device__ __forceinline__ float b2f(unsigned short u) {
    return __uint_as_float(((unsigned)u) << 16);
}
__device__ __forceinline__ unsigned short f2b(float f) {
    unsigned u = __float_as_uint(f);
    u += 0x7fffu + ((u >> 16) & 1u);     // round-to-nearest-even
    return (unsigned short)(u >> 16);
}
// ---- int8 unpack (sdwa sign-extend byte -> f32) ----
__device__ __forceinline__ void i8_unpack4(unsigned u, float* z) {
    z[0] = (float)((int)(u << 24) >> 24);
    z[1] = (float)((int)(u << 16) >> 24);
    z[2] = (float)((int)(u <<  8) >> 24);
    z[3] = (float)((int)u >> 24);
}

// ---- pack W[r] (row-major KxN fp32) into MFMA B-fragment order, bf16 ----
template<int K, int N>
__device__ __forceinline__ void pack_w_dev(const float* __restrict__ W,
                                           unsigned short* __restrict__ P, int t) {
    const int KS = K / 32, NT = N / 16;
    int lane = t & 63;
    int fid = t >> 6;
    if (fid >= NREL * NT * KS) return;
    int ks = fid % KS;
    int nt = (fid / KS) % NT;
    int r  = fid / (KS * NT);
    int n  = nt * 16 + (lane & 15);
    int k0 = ks * 32 + (lane >> 4) * 8;
    const float* Wr = W + (size_t)r * K * N;
    unsigned short o[8];
#pragma unroll
    for (int j = 0; j < 8; j++) o[j] = f2b(Wr[(size_t)(k0 + j) * N + n]);
    unsigned short* dst = P + (size_t)fid * 512 + lane * 8;
    *(ushort4*)&dst[0] = *(ushort4*)&o[0];
    *(ushort4*)&dst[4] = *(ushort4*)&o[4];
}

// ---- fused prep: x->bf16 cast | pack W1 | pack W2 (grid-partitioned) ----
#define CAST_BLOCKS (NNODES * IND / 4 / 256)          // 7500
#define PACK1_BLOCKS (NREL * (C1/16) * (IND/32) / 4)  // 48
#define PACK2_BLOCKS (NREL * (C2/16) * (C1/32) / 4)   // 48
__global__ void prep_kernel(const float* __restrict__ x, unsigned short* __restrict__ Xh,
                            const float* __restrict__ W1, unsigned short* __restrict__ P1,
                            const float* __restrict__ W2, unsigned short* __restrict__ P2) {
    int b = blockIdx.x;
    if (b < CAST_BLOCKS) {
        int i = (b * 256 + threadIdx.x) * 4;
        float4 v = *(const float4*)&x[i];
        ushort4 o = { f2b(v.x), f2b(v.y), f2b(v.z), f2b(v.w) };
        *(ushort4*)&Xh[i] = o;
    } else if (b < CAST_BLOCKS + PACK1_BLOCKS) {
        pack_w_dev<IND, C1>(W1, P1, (b - CAST_BLOCKS) * 256 + threadIdx.x);
    } else {
        pack_w_dev<C1, C2>(W2, P2, (b - CAST_BLOCKS - PACK1_BLOCKS) * 256 + threadIdx.x);
    }
}

// ---- MFMA GEMM + fused coeff, one (relation, 64-row tile) per block ----
// I8OUT=0: Zh bf16 out (layer 1).  I8OUT=1: Z8 int8 + per-row scaleZ out (layer 2).
// el/er always computed from pre-quant bf16 tile.
template<int K, int N, int I8OUT>
__global__ __launch_bounds__(256) void mfma_gemm(
    const unsigned short* __restrict__ Ah, const unsigned short* __restrict__ Bp,
    const float* __restrict__ al, const float* __restrict__ ar,
    unsigned short* __restrict__ Zh, unsigned char* __restrict__ Z8,
    float* __restrict__ scaleZ, float* __restrict__ el, float* __restrict__ er)
{
    const int KS = K / 32, NT = N / 16, MT = 64, NP = N + 4;
    const int wave = threadIdx.x >> 6, lane = threadIdx.x & 63;
    const int r  = blockIdx.y;
    const int m0 = blockIdx.x * MT;
    const int fcol = lane & 15, quad = lane >> 4;

    __shared__ unsigned short zs[MT * (N + 4)];
    __shared__ float smax[MT][NHEADS];
    __shared__ float rsh[MT];

    // A-frags for this wave's 16-row tile (A[m][k=quad*8+j], 16B/lane contiguous)
    int m = m0 + wave * 16 + fcol;
    if (m >= NNODES) m = NNODES - 1;           // clamp; padded rows never consumed
    bf16x8 afrag[KS];
    const unsigned short* arow = Ah + (size_t)m * K + quad * 8;
#pragma unroll
    for (int ks = 0; ks < KS; ks++) afrag[ks] = *(const bf16x8*)(arow + ks * 32);

    f32x4 acc[NT];
#pragma unroll
    for (int nt = 0; nt < NT; nt++) { f32x4 z = {0.f,0.f,0.f,0.f}; acc[nt] = z; }

    const unsigned short* Bpr = Bp + (size_t)r * NT * KS * 512;
    for (int ks = 0; ks < KS; ks++) {
        bf16x8 b[NT];
#pragma unroll
        for (int nt = 0; nt < NT; nt++)
            b[nt] = *(const bf16x8*)(Bpr + ((size_t)nt * KS + ks) * 512 + lane * 8);
#pragma unroll
        for (int nt = 0; nt < NT; nt++)
            acc[nt] = __builtin_amdgcn_mfma_f32_16x16x32_bf16(afrag[ks], b[nt], acc[nt], 0, 0, 0);
    }

    // C/D dump: row = wave*16 + quad*4 + q, col = nt*16 + fcol (NP pad: conflict-free)
    {
        int lrow = wave * 16 + quad * 4;
#pragma unroll
        for (int nt = 0; nt < NT; nt++)
#pragma unroll
            for (int q = 0; q < 4; q++)
                zs[(lrow + q) * NP + nt * 16 + fcol] = f2b(acc[nt][q]);
    }
    __syncthreads();

    if (!I8OUT) {
        // coalesced bf16 Z copy (uint2 = 4 bf16)
        uint2* zo = (uint2*)(Zh + ((size_t)r * MPAD + m0) * N);
        for (int i = threadIdx.x; i < MT * N / 4; i += 256) {
            int row = i / (N / 4), c4 = i % (N / 4);
            zo[i] = *(const uint2*)&zs[row * NP + c4 * 4];
        }
    }
    // fused coeff (+ per-(row,head) maxabs if I8OUT)
    {
        const int D = N / NHEADS;
        int row = threadIdx.x >> 2, h = threadIdx.x & 3;   // MT*NHEADS == 256
        int n = m0 + row;
        const float* alp = al + ((size_t)r * NHEADS + h) * D;
        const float* arp = ar + ((size_t)r * NHEADS + h) * D;
        const unsigned short* zp = zs + row * NP + h * D;
        float sl = 0.f, sr = 0.f, am = 0.f;
#pragma unroll
        for (int d0 = 0; d0 < D; d0 += 4) {
            uint2 u = *(const uint2*)&zp[d0];
            float z0 = b2f((unsigned short)(u.x & 0xffff));
            float z1 = b2f((unsigned short)(u.x >> 16));
            float z2 = b2f((unsigned short)(u.y & 0xffff));
            float z3 = b2f((unsigned short)(u.y >> 16));
            sl = fmaf(z0, alp[d0], sl);     sr = fmaf(z0, arp[d0], sr);
            sl = fmaf(z1, alp[d0 + 1], sl); sr = fmaf(z1, arp[d0 + 1], sr);
            sl = fmaf(z2, alp[d0 + 2], sl); sr = fmaf(z2, arp[d0 + 2], sr);
            sl = fmaf(z3, alp[d0 + 3], sl); sr = fmaf(z3, arp[d0 + 3], sr);
            if (I8OUT)
                am = fmaxf(am, fmaxf(fmaxf(fabsf(z0), fabsf(z1)),
                                     fmaxf(fabsf(z2), fabsf(z3))));
        }
        if (n < NNODES) {
            el[((size_t)r * NNODES + n) * NHEADS + h] = sl;
            er[((size_t)r * NNODES + n) * NHEADS + h] = sr;
        }
        if (I8OUT) smax[row][h] = am;
    }
    if (I8OUT) {
        __syncthreads();
        if (threadIdx.x < MT) {
            float m4 = fmaxf(fmaxf(smax[threadIdx.x][0], smax[threadIdx.x][1]),
                             fmaxf(smax[threadIdx.x][2], smax[threadIdx.x][3]));
            scaleZ[(size_t)r * MPAD + m0 + threadIdx.x] = m4 * (1.f / 127.f);
            rsh[threadIdx.x] = (m4 > 0.f) ? 127.f / m4 : 0.f;
        }
        __syncthreads();
        // int8 pack: dword = 4 channels
        unsigned char* zo = Z8 + ((size_t)r * MPAD + m0) * N;
        for (int i = threadIdx.x; i < MT * N / 4; i += 256) {
            int row = i / (N / 4), c4 = i % (N / 4);
            float rs = rsh[row];
            uint2 u = *(const uint2*)&zs[row * NP + c4 * 4];
            int q0 = __float2int_rn(b2f((unsigned short)(u.x & 0xffff)) * rs);
            int q1 = __float2int_rn(b2f((unsigned short)(u.x >> 16)) * rs);
            int q2 = __float2int_rn(b2f((unsigned short)(u.y & 0xffff)) * rs);
            int q3 = __float2int_rn(b2f((unsigned short)(u.y >> 16)) * rs);
            unsigned w = (q0 & 0xff) | ((q1 & 0xff) << 8) |
                         ((q2 & 0xff) << 16) | ((unsigned)(q3 & 0xff) << 24);
            *(unsigned*)&zo[(size_t)row * N + c4 * 4] = w;
        }
    }
}

// ---- build dst-bucketed adjacency: buck[(r*N+d)*CAP + i] = src ----
__global__ void bucket_fill(const int* __restrict__ src, const int* __restrict__ dst,
                            unsigned* __restrict__ cnt, int* __restrict__ buck) {
    int gid = blockIdx.x * blockDim.x + threadIdx.x;
    if (gid >= NREL * NEDGES) return;
    int r = gid / NEDGES;
    int d = dst[gid];
    int base = r * NNODES + d;
    unsigned pos = atomicAdd(&cnt[base], 1u);
    if (pos < CAP) buck[(size_t)base * CAP + pos] = src[gid];
}

__device__ __forceinline__ float wave_max(float t) {
#pragma unroll
    for (int o = 1; o < 64; o <<= 1) t = fmaxf(t, __shfl_xor(t, o, 64));
    return t;
}
__device__ __forceinline__ float wave_sum(float t) {
#pragma unroll
    for (int o = 1; o < 64; o <<= 1) t += __shfl_xor(t, o, 64);
    return t;
}

// ---- fused layer-1 aggregate: edge softmax + bf16 gather + relu/bias -> bf16 h ----
// one wave per node; lane owns channels 2*lane, 2*lane+1 of C1=128
__global__ __launch_bounds__(256) void gat_gather1(
    const unsigned* __restrict__ cnt, const int* __restrict__ buck,
    const float* __restrict__ el, const float* __restrict__ er,
    const unsigned short* __restrict__ Zh, const float* __restrict__ b1,
    unsigned short* __restrict__ hbh)
{
    __shared__ float atab[4][4 * 65];    // per-wave alpha table, stride 65 (bank-spread)
    int wave = threadIdx.x >> 6, lane = threadIdx.x & 63;
    int n = blockIdx.x * 4 + wave;
    if (n >= NNODES) return;
    const int h0 = lane >> 4;            // head of channels 2*lane..2*lane+1 (D=32)
    float accx = 0.f, accy = 0.f;
    for (int r = 0; r < NREL; r++) {
        int base = r * NNODES + n;
        int c = (int)cnt[base]; c = c < CAP ? c : CAP;
        if (c == 0) continue;
        int s_lane = (lane < c) ? buck[(size_t)base * CAP + lane] : -1;
        float lg[4];
        if (s_lane >= 0) {
            const float4 e4 = *(const float4*)&el[((size_t)r * NNODES + s_lane) * NHEADS];
            const float4 r4 = *(const float4*)&er[(size_t)base * NHEADS];
            float v;
            v = e4.x + r4.x; lg[0] = v > 0.f ? v : NEG_SLOPE * v;
            v = e4.y + r4.y; lg[1] = v > 0.f ? v : NEG_SLOPE * v;
            v = e4.z + r4.z; lg[2] = v > 0.f ? v : NEG_SLOPE * v;
            v = e4.w + r4.w; lg[3] = v > 0.f ? v : NEG_SLOPE * v;
        } else {
            lg[0] = lg[1] = lg[2] = lg[3] = -INFINITY;
        }
#pragma unroll
        for (int h = 0; h < 4; h++) {
            float m = wave_max(lg[h]);
            float w = (lane < c) ? __expf(lg[h] - m) : 0.f;
            float den = wave_sum(w);
            atab[wave][h * 65 + lane] = w / den;   // wave-private; no barrier
        }
        const unsigned short* Zr = Zh + (size_t)r * MPAD * C1;
        const float* at = atab[wave] + h0 * 65;
        int j = 0;
        for (; j + 3 < c; j += 4) {
            int s0 = __builtin_amdgcn_readlane(s_lane, j);
            int s1 = __builtin_amdgcn_readlane(s_lane, j + 1);
            int s2 = __builtin_amdgcn_readlane(s_lane, j + 2);
            int s3 = __builtin_amdgcn_readlane(s_lane, j + 3);
            const ushort2 za = *(const ushort2*)&Zr[(size_t)s0 * C1 + 2 * lane];
            const ushort2 zb = *(const ushort2*)&Zr[(size_t)s1 * C1 + 2 * lane];
            const ushort2 zc = *(const ushort2*)&Zr[(size_t)s2 * C1 + 2 * lane];
            const ushort2 zd = *(const ushort2*)&Zr[(size_t)s3 * C1 + 2 * lane];
            float a0 = at[j], a1 = at[j + 1], a2 = at[j + 2], a3 = at[j + 3];
            accx = fmaf(a0, b2f(za.x), accx); accy = fmaf(a0, b2f(za.y), accy);
            accx = fmaf(a1, b2f(zb.x), accx); accy = fmaf(a1, b2f(zb.y), accy);
            accx = fmaf(a2, b2f(zc.x), accx); accy = fmaf(a2, b2f(zc.y), accy);
            accx = fmaf(a3, b2f(zd.x), accx); accy = fmaf(a3, b2f(zd.y), accy);
        }
        for (; j < c; j++) {
            int s = __builtin_amdgcn_readlane(s_lane, j);
            float a0 = at[j];
            const ushort2 z2 = *(const ushort2*)&Zr[(size_t)s * C1 + 2 * lane];
            accx = fmaf(a0, b2f(z2.x), accx);
            accy = fmaf(a0, b2f(z2.y), accy);
        }
    }
    int cch = 2 * lane;
    float bx = b1[cch]     + b1[C1 + cch]     + b1[2 * C1 + cch];
    float by = b1[cch + 1] + b1[C1 + cch + 1] + b1[2 * C1 + cch + 1];
    ushort2 o;
    o.x = f2b(fmaxf(accx + bx, 0.f));
    o.y = f2b(fmaxf(accy + by, 0.f));
    *(ushort2*)&hbh[(size_t)n * C1 + cch] = o;
}

// ---- fused layer-2 aggregate: edge softmax + int8 gather + head-mean/bias ----
// one wave per node; lane owns channels 4*lane..4*lane+3 of C2=256 (1 dword int8)
// per-row dequant scale folded into the alpha table.
__global__ __launch_bounds__(256) void gat_gather2(
    const unsigned* __restrict__ cnt, const int* __restrict__ buck,
    const float* __restrict__ el, const float* __restrict__ er,
    const unsigned char* __restrict__ Z8, const float* __restrict__ scaleZ,
    const float* __restrict__ b2, float* __restrict__ out)
{
    __shared__ float atab[4][4 * 65];
    int wave = threadIdx.x >> 6, lane = threadIdx.x & 63;
    int n = blockIdx.x * 4 + wave;
    if (n >= NNODES) return;
    const int h0 = lane >> 4;            // head of channels 4*lane.. (D=64)
    float4 acc = {0.f, 0.f, 0.f, 0.f};
    for (int r = 0; r < NREL; r++) {
        int base = r * NNODES + n;
        int c = (int)cnt[base]; c = c < CAP ? c : CAP;
        if (c == 0) continue;
        int s_lane = (lane < c) ? buck[(size_t)base * CAP + lane] : -1;
        float lg[4];
        float scl = 0.f;
        if (s_lane >= 0) {
            scl = scaleZ[(size_t)r * MPAD + s_lane];
            const float4 e4 = *(const float4*)&el[((size_t)r * NNODES + s_lane) * NHEADS];
            const float4 r4 = *(const float4*)&er[(size_t)base * NHEADS];
            float v;
            v = e4.x + r4.x; lg[0] = v > 0.f ? v : NEG_SLOPE * v;
            v = e4.y + r4.y; lg[1] = v > 0.f ? v : NEG_SLOPE * v;
            v = e4.z + r4.z; lg[2] = v > 0.f ? v : NEG_SLOPE * v;
            v = e4.w + r4.w; lg[3] = v > 0.f ? v : NEG_SLOPE * v;
        } else {
            lg[0] = lg[1] = lg[2] = lg[3] = -INFINITY;
        }
#pragma unroll
        for (int h = 0; h < 4; h++) {
            float m = wave_max(lg[h]);
            float w = (lane < c) ? __expf(lg[h] - m) : 0.f;
            float den = wave_sum(w);
            atab[wave][h * 65 + lane] = (w / den) * scl;   // alpha * dequant scale
        }
        const unsigned char* Zr = Z8 + (size_t)r * MPAD * C2 + 4 * lane;
        const float* at = atab[wave] + h0 * 65;
        int j = 0;
        for (; j + 3 < c; j += 4) {
            int s0 = __builtin_amdgcn_readlane(s_lane, j);
            int s1 = __builtin_amdgcn_readlane(s_lane, j + 1);
            int s2 = __builtin_amdgcn_readlane(s_lane, j + 2);
            int s3 = __builtin_amdgcn_readlane(s_lane, j + 3);
            unsigned ua = *(const unsigned*)&Zr[(size_t)s0 * C2];
            unsigned ub = *(const unsigned*)&Zr[(size_t)s1 * C2];
            unsigned uc = *(const unsigned*)&Zr[(size_t)s2 * C2];
            unsigned ud = *(const unsigned*)&Zr[(size_t)s3 * C2];
            float a0 = at[j], a1 = at[j + 1], a2 = at[j + 2], a3 = at[j + 3];
            float z[4];
            i8_unpack4(ua, z);
            acc.x = fmaf(a0, z[0], acc.x); acc.y = fmaf(a0, z[1], acc.y);
            acc.z = fmaf(a0, z[2], acc.z); acc.w = fmaf(a0, z[3], acc.w);
            i8_unpack4(ub, z);
            acc.x = fmaf(a1, z[0], acc.x); acc.y = fmaf(a1, z[1], acc.y);
            acc.z = fmaf(a1, z[2], acc.z); acc.w = fmaf(a1, z[3], acc.w);
            i8_unpack4(uc, z);
            acc.x = fmaf(a2, z[0], acc.x); acc.y = fmaf(a2, z[1], acc.y);
            acc.z = fmaf(a2, z[2], acc.z); acc.w = fmaf(a2, z[3], acc.w);
            i8_unpack4(ud, z);
            acc.x = fmaf(a3, z[0], acc.x); acc.y = fmaf(a3, z[1], acc.y);
            acc.z = fmaf(a3, z[2], acc.z); acc.w = fmaf(a3, z[3], acc.w);
        }
        for (; j < c; j++) {
            int s = __builtin_amdgcn_readlane(s_lane, j);
            float a0 = at[j];
            float z[4];
            i8_unpack4(*(const unsigned*)&Zr[(size_t)s * C2], z);
            acc.x = fmaf(a0, z[0], acc.x); acc.y = fmaf(a0, z[1], acc.y);
            acc.z = fmaf(a0, z[2], acc.z); acc.w = fmaf(a0, z[3], acc.w);
        }
    }
    int cch = 4 * lane;
#pragma unroll
    for (int q = 0; q < 4; q++) {
        float b = b2[cch + q] + b2[C2 + cch + q] + b2[2 * C2 + cch + q];
        (&acc.x)[q] += b;
    }
    acc.x += __shfl_xor(acc.x, 16, 64); acc.y += __shfl_xor(acc.y, 16, 64);
    acc.z += __shfl_xor(acc.z, 16, 64); acc.w += __shfl_xor(acc.w, 16, 64);
    acc.x += __shfl_xor(acc.x, 32, 64); acc.y += __shfl_xor(acc.y, 32, 64);
    acc.z += __shfl_xor(acc.z, 32, 64); acc.w += __shfl_xor(acc.w, 32, 64);
    if (lane < 16) {
        float4 o;
        o.x = 0.25f * acc.x; o.y = 0.25f * acc.y;
        o.z = 0.25f * acc.z; o.w = 0.25f * acc.w;
        *(float4*)&out[(size_t)n * OUTD + 4 * lane] = o;
    }
}

extern "C" void kernel_launch(void* const* d_in, const int* in_sizes, int n_in,
                              void* d_out, int out_size, void* d_ws, size_t ws_size,
                              hipStream_t stream) {
    (void)in_sizes; (void)n_in; (void)out_size; (void)ws_size;
    const float* x   = (const float*)d_in[0];
    const int*   src = (const int*)d_in[1];
    const int*   dst = (const int*)d_in[2];
    const float* W1  = (const float*)d_in[3];
    const float* al1 = (const float*)d_in[4];
    const float* ar1 = (const float*)d_in[5];
    const float* b1  = (const float*)d_in[6];
    const float* W2  = (const float*)d_in[7];
    const float* al2 = (const float*)d_in[8];
    const float* ar2 = (const float*)d_in[9];
    const float* b2  = (const float*)d_in[10];
    float* out = (float*)d_out;

    // ---- workspace layout (float-offset based; every chunk 16B-aligned) ----
    float* ws = (float*)d_ws;
    size_t off = 0;
    unsigned short* Zh  = (unsigned short*)(ws + off); off += (size_t)NREL * MPAD * C1 / 2; // bf16 layer-1 Z
    unsigned char*  Z8  = (unsigned char*)(ws + off);  off += (size_t)NREL * MPAD * C2 / 4; // int8 layer-2 Z
    float* scaleZ = ws + off; off += (size_t)NREL * MPAD;                                   // per-row dequant
    unsigned short* Xh  = (unsigned short*)(ws + off); off += (size_t)NNODES * IND / 2;
    unsigned short* hbh = (unsigned short*)(ws + off); off += (size_t)NNODES * C1 / 2;
    unsigned short* P1  = (unsigned short*)(ws + off); off += (size_t)NREL * (C1/16) * (IND/32) * 512 / 2;
    unsigned short* P2  = (unsigned short*)(ws + off); off += (size_t)NREL * (C2/16) * (C1/32) * 512 / 2;
    float* el  = ws + off; off += (size_t)NREL * NNODES * NHEADS;
    float* er  = ws + off; off += (size_t)NREL * NNODES * NHEADS;
    unsigned* cnt = (unsigned*)(ws + off); off += (size_t)NREL * NNODES;
    int* buck  = (int*)(ws + off); off += (size_t)NREL * NNODES * CAP;

    const int TB = 256;

    // ---- adjacency build + fused cast/pack prep ----
    hipMemsetAsync(cnt, 0, (size_t)NREL * NNODES * sizeof(unsigned), stream);
    bucket_fill<<<(NREL * NEDGES + TB - 1) / TB, TB, 0, stream>>>(src, dst, cnt, buck);
    prep_kernel<<<CAST_BLOCKS + PACK1_BLOCKS + PACK2_BLOCKS, TB, 0, stream>>>(
        x, Xh, W1, P1, W2, P2);

    // ================= layer 1 =================
    {
        dim3 grid(MPAD / 64, NREL);
        mfma_gemm<IND, C1, 0><<<grid, 256, 0, stream>>>(Xh, P1, al1, ar1,
                                                        Zh, nullptr, nullptr, el, er);
    }
    gat_gather1<<<(NNODES + 3) / 4, 256, 0, stream>>>(cnt, buck, el, er, Zh, b1, hbh);

    // ================= layer 2 =================
    {
        dim3 grid(MPAD / 64, NREL);
        mfma_gemm<C1, C2, 1><<<grid, 256, 0, stream>>>(hbh, P2, al2, ar2,
                                                       nullptr, Z8, scaleZ, el, er);
    }
    gat_gather2<<<(NNODES + 3) / 4, 256, 0, stream>>>(cnt, buck, el, er, Z8, scaleZ, b2, out);
}